// Round 2
// baseline (73.582 us; speedup 1.0000x reference)
//
#include <hip/hip_runtime.h>

#define N_NODES 512
#define DIM 128
#define MAX_PATH 5
#define NUM_EDGES 8192

// Kernel 1: T[e][p] = dot(edge_embedding[e, :], edge_vector[p, :])
// One wave (64 lanes) per edge; each lane holds 2 consecutive floats (float2).
__global__ void edge_dot_table_kernel(const float* __restrict__ edge_embedding,
                                      const float* __restrict__ edge_vector,
                                      float* __restrict__ table) {
    const int lane = threadIdx.x & 63;
    const int wave_in_block = threadIdx.x >> 6;
    const int e = blockIdx.x * (blockDim.x >> 6) + wave_in_block;
    if (e >= NUM_EDGES) return;

    const float2 eb = *reinterpret_cast<const float2*>(
        &edge_embedding[e * DIM + lane * 2]);

#pragma unroll
    for (int p = 0; p < MAX_PATH; ++p) {
        const float2 ev = *reinterpret_cast<const float2*>(
            &edge_vector[p * DIM + lane * 2]);
        float partial = eb.x * ev.x + eb.y * ev.y;
#pragma unroll
        for (int off = 32; off >= 1; off >>= 1)
            partial += __shfl_xor(partial, off, 64);
        if (lane == 0) table[e * MAX_PATH + p] = partial;
    }
}

// Masked sum of one pair's 5 path entries + divide by count.
// All table indices are compile-time-structured (no runtime-indexed local
// arrays -> everything stays in VGPRs).
__device__ __forceinline__ float pair_enc(int e0, int e1, int e2, int e3, int e4,
                                          const float* __restrict__ table) {
    float s = 0.0f;
    int c = 0;
    if (e0 >= 0) { s += table[e0 * MAX_PATH + 0]; ++c; }
    if (e1 >= 0) { s += table[e1 * MAX_PATH + 1]; ++c; }
    if (e2 >= 0) { s += table[e2 * MAX_PATH + 2]; ++c; }
    if (e3 >= 0) { s += table[e3 * MAX_PATH + 3]; ++c; }
    if (e4 >= 0) { s += table[e4 * MAX_PATH + 4]; ++c; }
    return s / (float)(c > 0 ? c : 1);
}

// Kernel 2: 4 (i,j) pairs per thread. 4 pairs * 5 ints = 80 B = 5 aligned
// int4 loads; 20 independent scalar gathers from the 160 KB table (L2/L3
// resident); one float4 store.
__global__ void edge_enc_kernel(const int* __restrict__ edge_paths,
                                const float* __restrict__ table,
                                float* __restrict__ out) {
    const int t = blockIdx.x * blockDim.x + threadIdx.x;   // 65536 threads
    const int q = t * 4;                                   // first pair index
    if (q >= N_NODES * N_NODES) return;

    const int4* p4 = reinterpret_cast<const int4*>(edge_paths + q * MAX_PATH);
    const int4 w0 = p4[0];
    const int4 w1 = p4[1];
    const int4 w2 = p4[2];
    const int4 w3 = p4[3];
    const int4 w4 = p4[4];

    float4 r;
    r.x = pair_enc(w0.x, w0.y, w0.z, w0.w, w1.x, table);
    r.y = pair_enc(w1.y, w1.z, w1.w, w2.x, w2.y, table);
    r.z = pair_enc(w2.z, w2.w, w3.x, w3.y, w3.z, table);
    r.w = pair_enc(w3.w, w4.x, w4.y, w4.z, w4.w, table);

    *reinterpret_cast<float4*>(out + q) = r;
}

extern "C" void kernel_launch(void* const* d_in, const int* in_sizes, int n_in,
                              void* d_out, int out_size, void* d_ws, size_t ws_size,
                              hipStream_t stream) {
    // d_in[0] = x (unused by reference)
    const float* edge_embedding = (const float*)d_in[1];   // (E, DIM) f32
    const int*   edge_paths     = (const int*)d_in[2];     // (N, N, P) i32
    const float* edge_vector    = (const float*)d_in[3];   // (P, DIM) f32
    float* out = (float*)d_out;                            // (N, N) f32

    float* table = (float*)d_ws;                           // E * MAX_PATH floats = 160 KB

    // Kernel 1: 8192 edges, 4 waves (256 threads) per block -> 2048 blocks.
    const int waves_per_block = 4;
    const int blocks1 = NUM_EDGES / waves_per_block;
    edge_dot_table_kernel<<<blocks1, waves_per_block * 64, 0, stream>>>(
        edge_embedding, edge_vector, table);

    // Kernel 2: 4 pairs per thread.
    const int pairs = N_NODES * N_NODES;
    const int threads2 = pairs / 4;                        // 65536
    const int blocks2 = threads2 / 256;                    // 256
    edge_enc_kernel<<<blocks2, 256, 0, stream>>>(edge_paths, table, out);
}